// Round 8
// baseline (6170.765 us; speedup 1.0000x reference)
//
#include <hip/hip_runtime.h>
#include <hip/hip_bf16.h>
#include <cstdint>
#include <cstddef>

typedef unsigned short u16;
typedef __bf16 bf16x8 __attribute__((ext_vector_type(8)));
typedef float f32x4 __attribute__((ext_vector_type(4)));
typedef float f32x4u __attribute__((ext_vector_type(4), aligned(4)));  // 4B-aligned vector load

#define IN_F   4096
#define OUT_F  4096
#define IC_N   409      // int(4096*0.1)
#define K_NON  3687     // 4096-409
#define K_HI0  3712     // 58*64: sigmoid boundary (BK-aligned)
#define K_LO0  4121
#define K_HI1  4530
#define K_END  4939
#define K_TOT  4992     // 78*64 = 156 chunks of 32
#define BATCHN 8192
#define NBODY  78       // bodies of 2 K-chunks (K=64)
#define T_SPLIT 58      // body where state transform applies (chunk 116 = k 3712)

__device__ __forceinline__ u16 f2bf(float f) {          // RNE fp32->bf16
  uint32_t u = __float_as_uint(f);
  uint32_t r = (u + 0x7FFFu + ((u >> 16) & 1u)) >> 16;
  return (u16)r;
}
__device__ __forceinline__ float bf2f(u16 h) {
  return __uint_as_float(((uint32_t)h) << 16);
}
__device__ __forceinline__ float coefj(int j) {
  return (j == 0 || j == IC_N - 1) ? 1.0f : 2.0f;
}

// ---------------- pack A (verified r5): one block per batch row
__global__ __launch_bounds__(256) void pack_a_kernel(const float* __restrict__ x,
                                                     u16* __restrict__ Ab) {
  __shared__ u16 hbuf[IC_N];
  __shared__ u16 lbuf[IC_N];
  const int row = blockIdx.x;
  const float* xr = x + (size_t)row * IN_F;
  for (int j = threadIdx.x; j < IC_N; j += 256) {
    const float v = xr[j] * coefj(j);
    const u16 h = f2bf(v);
    hbuf[j] = h;
    lbuf[j] = f2bf(v - bf2f(h));
  }
  __syncthreads();
  u16* outr = Ab + (size_t)row * K_TOT;
  for (int c8 = threadIdx.x; c8 < K_TOT / 8; c8 += 256) {
    const int kb = c8 * 8;
    u16 tmp[8] __attribute__((aligned(16)));
    if (kb + 8 <= K_NON) {
      const float* s = xr + IC_N + kb;
      const f32x4u v0 = *(const f32x4u*)s;
      const f32x4u v1 = *(const f32x4u*)(s + 4);
#pragma unroll
      for (int e = 0; e < 4; ++e) { tmp[e] = f2bf(v0[e]); tmp[4 + e] = f2bf(v1[e]); }
    } else if (kb < K_HI0) {
#pragma unroll
      for (int e = 0; e < 8; ++e) {
        const int k = kb + e;
        tmp[e] = (k < K_NON) ? f2bf(xr[IC_N + k]) : (u16)0;
      }
    } else {
#pragma unroll
      for (int e = 0; e < 8; ++e) {
        const int k = kb + e;
        u16 o;
        if (k < K_LO0)      o = hbuf[k - K_HI0];
        else if (k < K_HI1) o = lbuf[k - K_LO0];
        else if (k < K_END) o = hbuf[k - K_HI1];
        else                o = 0;
        tmp[e] = o;
      }
    }
    *(int4*)(outr + kb) = *(const int4*)tmp;
  }
}

// ---------------- pack B (verified r5): one block per output row
__global__ __launch_bounds__(256) void pack_b_kernel(const float* __restrict__ Wnon,
                                                     const float* __restrict__ Wnmda,
                                                     u16* __restrict__ Bb) {
  __shared__ u16 hbuf[IC_N];
  __shared__ u16 lbuf[IC_N];
  const int row = blockIdx.x;
  const float* wr = Wnon + (size_t)row * K_NON;
  const float* wc = Wnmda + (size_t)row * IC_N;
  for (int j = threadIdx.x; j < IC_N; j += 256) {
    const float v = wc[j];
    const u16 h = f2bf(v);
    hbuf[j] = h;
    lbuf[j] = f2bf(v - bf2f(h));
  }
  __syncthreads();
  u16* outr = Bb + (size_t)row * K_TOT;
  for (int c8 = threadIdx.x; c8 < K_TOT / 8; c8 += 256) {
    const int kb = c8 * 8;
    u16 tmp[8] __attribute__((aligned(16)));
    if (kb + 8 <= K_NON) {
      const float* s = wr + kb;
      const f32x4u v0 = *(const f32x4u*)s;
      const f32x4u v1 = *(const f32x4u*)(s + 4);
#pragma unroll
      for (int e = 0; e < 4; ++e) { tmp[e] = f2bf(v0[e]); tmp[4 + e] = f2bf(v1[e]); }
    } else if (kb < K_HI0) {
#pragma unroll
      for (int e = 0; e < 8; ++e) {
        const int k = kb + e;
        tmp[e] = (k < K_NON) ? f2bf(wr[k]) : (u16)0;
      }
    } else {
#pragma unroll
      for (int e = 0; e < 8; ++e) {
        const int k = kb + e;
        u16 o;
        if (k < K_LO0)      o = hbuf[k - K_HI0];
        else if (k < K_HI1) o = hbuf[k - K_LO0];
        else if (k < K_END) o = lbuf[k - K_HI1];
        else                o = 0;
        tmp[e] = o;
      }
    }
    *(int4*)(outr + kb) = *(const int4*)tmp;
  }
}

// ---------------- fused GEMM: 256x256 tile, 8 waves, 64 KiB LDS (2 blocks/CU),
// 2-deep K=32 chunk ring, read-ahead single-barrier pipeline
#define GLOAD16(gp, lp)                                           \
  __builtin_amdgcn_global_load_lds(                               \
      (const __attribute__((address_space(1))) void*)(gp),        \
      (__attribute__((address_space(3))) void*)(lp), 16, 0, 0)

#define MEMFENCE() asm volatile("" ::: "memory")
#define BAR() do { MEMFENCE(); __builtin_amdgcn_s_barrier(); MEMFENCE(); } while (0)
#define LGKM0() asm volatile("s_waitcnt lgkmcnt(0)" ::: "memory")
#define VM0()   asm volatile("s_waitcnt vmcnt(0)" ::: "memory")
#define VNONE   ((void)0)

// LDS: A-ring slots [0,16K),[16K,32K); B-ring slots [32K,48K),[48K,64K).
// Slot = 256 rows x 32 bf16. Swizzle: pair=row>>1;
// phys = pair*128 + ((((row&1)<<2)|chunk16) ^ (pair&7))*16   (involution)
#define RD_AF(SET, SLOT, MH) do {                                      \
    _Pragma("unroll")                                                  \
    for (int mm = 0; mm < 4; ++mm)                                     \
      SET[mm] = *(const bf16x8*)(LDSc + (SLOT) * 16384 +               \
                 (wRow + (MH) * 64 + mm * 16) * 64 + laneOff);         \
  } while (0)
#define RD_BF(SET, SLOT) do {                                          \
    _Pragma("unroll")                                                  \
    for (int n = 0; n < 4; ++n)                                        \
      SET[n] = *(const bf16x8*)(LDSc + 32768 + (SLOT) * 16384 +        \
                (wCol + n * 16) * 64 + laneOff);                       \
  } while (0)

#define PHASE(AFC, BFC, MH, NEXT_READS, STAGE_STMT, VMSTMT) do {       \
    LGKM0();                                                           \
    NEXT_READS;                                                        \
    STAGE_STMT;                                                        \
    __builtin_amdgcn_sched_barrier(0);                                 \
    __builtin_amdgcn_s_setprio(1);                                     \
    _Pragma("unroll")                                                  \
    for (int mm = 0; mm < 4; ++mm)                                     \
      _Pragma("unroll")                                                \
      for (int n = 0; n < 4; ++n)                                      \
        acc[(MH) * 4 + mm][n] = __builtin_amdgcn_mfma_f32_16x16x32_bf16( \
            AFC[mm], BFC[n], acc[(MH) * 4 + mm][n], 0, 0, 0);          \
    __builtin_amdgcn_s_setprio(0);                                     \
    VMSTMT;                                                            \
    BAR();                                                             \
  } while (0)

__global__ __launch_bounds__(512, 4) void gemm_fused_kernel(
    const u16* __restrict__ Ab, const u16* __restrict__ Bb,
    const float* __restrict__ bnon, float* __restrict__ out) {
  __shared__ __attribute__((aligned(16))) u16 LDSu[32768];   // 64 KiB
  char* LDSc = (char*)LDSu;

  const int bid = blockIdx.x;                      // 512 blocks = 32 x 16 tiles
  const int swz = ((bid & 7) << 6) | (bid >> 3);   // bijective XCD swizzle
  const int bm = swz >> 4, bn = swz & 15;
  const int rowBase = bm * 256, colBase = bn * 256;

  const int tid  = threadIdx.x;
  const int w    = tid >> 6, lane = tid & 63;
  const int wm = w >> 2, wn = w & 3;               // 2 x 4 wave grid
  const int wRow = wm * 128, wCol = wn * 64;       // per-wave 128x64 output
  const int l15 = lane & 15, g = lane >> 4;

  // per-lane swizzled read offset (adds to row*64 cleanly)
  const int laneOff = ((l15 >> 1) << 7) +
                      (((((l15 & 1) << 2) | g) ^ ((l15 >> 1) & 7)) << 4);

  // staging: linear LDS dest (d = issue*8192 + tid*16), inverse-swizzled global src
  int rowS[2], colS[2];
#pragma unroll
  for (int is = 0; is < 2; ++is) {
    const int d = is * 8192 + tid * 16;
    const int b = d ^ ((d >> 3) & 0x70);
    rowS[is] = ((b >> 7) << 1) | ((b >> 6) & 1);
    colS[is] = (b >> 1) & 31;
  }
  const u16* pA0 = Ab + (size_t)(rowBase + rowS[0]) * K_TOT + colS[0];
  const u16* pA1 = Ab + (size_t)(rowBase + rowS[1]) * K_TOT + colS[1];
  const u16* pB0 = Bb + (size_t)(colBase + rowS[0]) * K_TOT + colS[0];
  const u16* pB1 = Bb + (size_t)(colBase + rowS[1]) * K_TOT + colS[1];

  // bias: load and fully retire so the vmcnt ledger stays clean
  float bn4[4];
#pragma unroll
  for (int n = 0; n < 4; ++n) bn4[n] = bnon[colBase + wCol + n * 16 + l15];
  asm volatile("" :: "v"(bn4[0]), "v"(bn4[1]), "v"(bn4[2]), "v"(bn4[3]));
  VM0();

  // stage A+B slots for ring slot s from k-offset koff (4 gloads)
  auto stage2 = [&](int slot, int koff) {
#pragma unroll
    for (int mat = 0; mat < 2; ++mat) {
      const u16* s0 = (mat ? pB0 : pA0) + koff;
      const u16* s1 = (mat ? pB1 : pA1) + koff;
      char* dst = LDSc + mat * 32768 + slot * 16384 + tid * 16;
      GLOAD16(s0, dst);
      GLOAD16(s1, dst + 8192);
    }
  };

  f32x4 acc[8][4] = {};
  bf16x8 afA[4], afB[4], bfrA[4], bfrB[4];

  // prologue: chunk 0 -> slot0, chunk 1 -> slot1 (8 gloads); retire chunk 0
  stage2(0, 0);
  stage2(1, 32);
  asm volatile("s_waitcnt vmcnt(4)" ::: "memory");  // chunk 0 (oldest 4) landed
  BAR();                                            // all waves' chunk-0 loads landed
  RD_AF(afA, 0, 0); RD_BF(bfrA, 0);                 // p0 operands

  // Body t: chunks c=2t (slot0), c+1 (slot1); stages chunks 2t+2 (p1), 2t+3 (p3).
  // VM0 at p0/p2 end = guard for slot staged one phase earlier (all-waves via VM->BAR).
  for (int t = 0; t < NBODY - 1; ++t) {
    if (t == T_SPLIT) {
      // acc == x_nc @ W_non^T complete; in-place: sigmoid(acc+b) - 1
#pragma unroll
      for (int m = 0; m < 8; ++m)
#pragma unroll
        for (int n = 0; n < 4; ++n)
#pragma unroll
          for (int j = 0; j < 4; ++j) {
            const float tv = acc[m][n][j] + bn4[n];
            acc[m][n][j] = 1.0f / (1.0f + __expf(-tv)) - 1.0f;
          }
    }
    const int k2 = (2 * t + 2) * 32, k3 = (2 * t + 3) * 32;
    PHASE(afA, bfrA, 0, RD_AF(afB, 0, 1),                      VNONE,         VM0());
    PHASE(afB, bfrA, 1, { RD_AF(afA, 1, 0); RD_BF(bfrB, 1); }, stage2(0, k2), VNONE);
    PHASE(afA, bfrB, 0, RD_AF(afB, 1, 1),                      VNONE,         VM0());
    PHASE(afB, bfrB, 1, { RD_AF(afA, 0, 0); RD_BF(bfrA, 0); }, stage2(1, k3), VNONE);
  }

  {   // tail body t = NBODY-1: chunks 154,155; no staging
    PHASE(afA, bfrA, 0, RD_AF(afB, 0, 1),                      VNONE, VM0());
    PHASE(afB, bfrA, 1, { RD_AF(afA, 1, 0); RD_BF(bfrB, 1); }, VNONE, VNONE);
    PHASE(afA, bfrB, 0, RD_AF(afB, 1, 1),                      VNONE, VNONE);
    PHASE(afB, bfrB, 1, VNONE,                                 VNONE, VNONE);
  }

  // epilogue: Hill. C/D layout col=lane&15, row=(lane>>4)*4+j  [m89/m91]
#pragma unroll
  for (int m = 0; m < 8; ++m) {
#pragma unroll
    for (int n = 0; n < 4; ++n) {
#pragma unroll
      for (int j = 0; j < 4; ++j) {
        const int r = rowBase + wRow + m * 16 + g * 4 + j;
        const int c = colBase + wCol + n * 16 + l15;
        const float pre = acc[m][n][j];
        const float xn = pre * pre;
        out[(size_t)r * OUT_F + c] = xn / (0.25f + xn);
      }
    }
  }
}

// ---------------- fallback (workspace too small): naive fp32
__global__ void naive_fused_kernel(const float* __restrict__ x,
                                   const float* __restrict__ Wnmda,
                                   const float* __restrict__ Wnon,
                                   const float* __restrict__ bnon,
                                   float* __restrict__ out) {
  const long long total = (long long)BATCHN * OUT_F;
  for (long long idx = (long long)blockIdx.x * blockDim.x + threadIdx.x;
       idx < total; idx += (long long)gridDim.x * blockDim.x) {
    const int b = (int)(idx / OUT_F);
    const int o = (int)(idx % OUT_F);
    float s = bnon[o];
    for (int k = 0; k < K_NON; ++k)
      s += x[(size_t)b * IN_F + IC_N + k] * Wnon[(size_t)o * K_NON + k];
    const float state = 1.0f / (1.0f + __expf(-s)) - 1.0f;
    float ca = 0.0f;
    for (int j = 0; j < IC_N; ++j)
      ca += x[(size_t)b * IN_F + j] * coefj(j) * Wnmda[(size_t)o * IC_N + j];
    const float pre = ca + state;
    const float xn = pre * pre;
    out[idx] = xn / (0.25f + xn);
  }
}

extern "C" void kernel_launch(void* const* d_in, const int* in_sizes, int n_in,
                              void* d_out, int out_size, void* d_ws, size_t ws_size,
                              hipStream_t stream) {
  const float* x     = (const float*)d_in[0];
  const float* Wnmda = (const float*)d_in[1];
  const float* Wnon  = (const float*)d_in[2];
  const float* bnon  = (const float*)d_in[3];
  float* out = (float*)d_out;

  const size_t needA = (size_t)BATCHN * K_TOT * sizeof(u16);  // ~81.8 MB
  const size_t needB = (size_t)OUT_F * K_TOT * sizeof(u16);   // ~40.9 MB

  if (ws_size < needA + needB) {
    naive_fused_kernel<<<8192, 256, 0, stream>>>(x, Wnmda, Wnon, bnon, out);
    return;
  }

  u16* Ab = (u16*)d_ws;
  u16* Bb = Ab + (size_t)BATCHN * K_TOT;

  pack_a_kernel<<<BATCHN, 256, 0, stream>>>(x, Ab);
  pack_b_kernel<<<OUT_F, 256, 0, stream>>>(Wnon, Wnmda, Bb);
  gemm_fused_kernel<<<512, 512, 0, stream>>>(Ab, Bb, bnon, out);
}

// Round 9
// 360.419 us; speedup vs baseline: 17.1211x; 17.1211x over previous
//
#include <hip/hip_runtime.h>
#include <hip/hip_bf16.h>
#include <cstdint>
#include <cstddef>

typedef unsigned short u16;
typedef __bf16 bf16x8 __attribute__((ext_vector_type(8)));
typedef float f32x4 __attribute__((ext_vector_type(4)));
typedef float f32x4u __attribute__((ext_vector_type(4), aligned(4)));  // 4B-aligned vector load

#define IN_F   4096
#define OUT_F  4096
#define IC_N   409      // int(4096*0.1)
#define K_NON  3687     // 4096-409
#define K_HI0  3712     // 58*64: sigmoid boundary (BK-aligned)
#define K_LO0  4121
#define K_HI1  4530
#define K_END  4939
#define K_TOT  4992     // 78*64
#define BATCHN 8192
#define NT     78       // K-tiles of 64
#define T_SPLIT 58      // body index where state transform applies

__device__ __forceinline__ u16 f2bf(float f) {          // RNE fp32->bf16
  uint32_t u = __float_as_uint(f);
  uint32_t r = (u + 0x7FFFu + ((u >> 16) & 1u)) >> 16;
  return (u16)r;
}
__device__ __forceinline__ float bf2f(u16 h) {
  return __uint_as_float(((uint32_t)h) << 16);
}
__device__ __forceinline__ float coefj(int j) {
  return (j == 0 || j == IC_N - 1) ? 1.0f : 2.0f;
}

// ---------------- pack A (verified r5): one block per batch row
__global__ __launch_bounds__(256) void pack_a_kernel(const float* __restrict__ x,
                                                     u16* __restrict__ Ab) {
  __shared__ u16 hbuf[IC_N];
  __shared__ u16 lbuf[IC_N];
  const int row = blockIdx.x;
  const float* xr = x + (size_t)row * IN_F;
  for (int j = threadIdx.x; j < IC_N; j += 256) {
    const float v = xr[j] * coefj(j);
    const u16 h = f2bf(v);
    hbuf[j] = h;
    lbuf[j] = f2bf(v - bf2f(h));
  }
  __syncthreads();
  u16* outr = Ab + (size_t)row * K_TOT;
  for (int c8 = threadIdx.x; c8 < K_TOT / 8; c8 += 256) {
    const int kb = c8 * 8;
    u16 tmp[8] __attribute__((aligned(16)));
    if (kb + 8 <= K_NON) {
      const float* s = xr + IC_N + kb;
      const f32x4u v0 = *(const f32x4u*)s;
      const f32x4u v1 = *(const f32x4u*)(s + 4);
#pragma unroll
      for (int e = 0; e < 4; ++e) { tmp[e] = f2bf(v0[e]); tmp[4 + e] = f2bf(v1[e]); }
    } else if (kb < K_HI0) {
#pragma unroll
      for (int e = 0; e < 8; ++e) {
        const int k = kb + e;
        tmp[e] = (k < K_NON) ? f2bf(xr[IC_N + k]) : (u16)0;
      }
    } else {
#pragma unroll
      for (int e = 0; e < 8; ++e) {
        const int k = kb + e;
        u16 o;
        if (k < K_LO0)      o = hbuf[k - K_HI0];
        else if (k < K_HI1) o = lbuf[k - K_LO0];
        else if (k < K_END) o = hbuf[k - K_HI1];
        else                o = 0;
        tmp[e] = o;
      }
    }
    *(int4*)(outr + kb) = *(const int4*)tmp;
  }
}

// ---------------- pack B (verified r5): one block per output row
__global__ __launch_bounds__(256) void pack_b_kernel(const float* __restrict__ Wnon,
                                                     const float* __restrict__ Wnmda,
                                                     u16* __restrict__ Bb) {
  __shared__ u16 hbuf[IC_N];
  __shared__ u16 lbuf[IC_N];
  const int row = blockIdx.x;
  const float* wr = Wnon + (size_t)row * K_NON;
  const float* wc = Wnmda + (size_t)row * IC_N;
  for (int j = threadIdx.x; j < IC_N; j += 256) {
    const float v = wc[j];
    const u16 h = f2bf(v);
    hbuf[j] = h;
    lbuf[j] = f2bf(v - bf2f(h));
  }
  __syncthreads();
  u16* outr = Bb + (size_t)row * K_TOT;
  for (int c8 = threadIdx.x; c8 < K_TOT / 8; c8 += 256) {
    const int kb = c8 * 8;
    u16 tmp[8] __attribute__((aligned(16)));
    if (kb + 8 <= K_NON) {
      const float* s = wr + kb;
      const f32x4u v0 = *(const f32x4u*)s;
      const f32x4u v1 = *(const f32x4u*)(s + 4);
#pragma unroll
      for (int e = 0; e < 4; ++e) { tmp[e] = f2bf(v0[e]); tmp[4 + e] = f2bf(v1[e]); }
    } else if (kb < K_HI0) {
#pragma unroll
      for (int e = 0; e < 8; ++e) {
        const int k = kb + e;
        tmp[e] = (k < K_NON) ? f2bf(wr[k]) : (u16)0;
      }
    } else {
#pragma unroll
      for (int e = 0; e < 8; ++e) {
        const int k = kb + e;
        u16 o;
        if (k < K_LO0)      o = hbuf[k - K_HI0];
        else if (k < K_HI1) o = hbuf[k - K_LO0];
        else if (k < K_END) o = lbuf[k - K_HI1];
        else                o = 0;
        tmp[e] = o;
      }
    }
    *(int4*)(outr + kb) = *(const int4*)tmp;
  }
}

// ---------------- fused GEMM: 256x256, BK=64, 8 waves, single-barrier read-ahead
// pipeline (verified r4 schedule; LGKM0 + sched_barrier removed -> compiler
// fine-grained lgkmcnt + ds_read/MFMA interleave)
#define GLOAD16(gp, lp)                                           \
  __builtin_amdgcn_global_load_lds(                               \
      (const __attribute__((address_space(1))) void*)(gp),        \
      (__attribute__((address_space(3))) void*)(lp), 16, 0, 0)

#define MEMFENCE() asm volatile("" ::: "memory")
#define BAR() do { MEMFENCE(); __builtin_amdgcn_s_barrier(); MEMFENCE(); } while (0)
#define VM6()   asm volatile("s_waitcnt vmcnt(6)" ::: "memory")
#define VM0()   asm volatile("s_waitcnt vmcnt(0)" ::: "memory")
#define VNONE   ((void)0)

#define RD_AF(SET, BW, KK, MH) do {                                    \
    _Pragma("unroll")                                                  \
    for (int mm = 0; mm < 4; ++mm)                                     \
      SET[mm] = *(const bf16x8*)(LDSc + (BW) * 65536 + (KK) * 16384 +  \
                 (wRow + (MH) * 64 + mm * 16) * 64 + laneOff);         \
  } while (0)
#define RD_BF(SET, BW, KK) do {                                        \
    _Pragma("unroll")                                                  \
    for (int n = 0; n < 4; ++n)                                        \
      SET[n] = *(const bf16x8*)(LDSc + (BW) * 65536 + 32768 +          \
                (KK) * 16384 + (wCol + n * 16) * 64 + laneOff);        \
  } while (0)

// Phase: issue next phase's operand reads + one slot refill; MFMA on current
// operands (compiler inserts fine-grained lgkmcnt for their deps); counted
// vmcnt; barrier. Hazard ledger identical to verified r4.
#define PHASE(AFC, BFC, MH, NEXT_READS, STAGE_STMT, VMSTMT) do {       \
    NEXT_READS;                                                        \
    STAGE_STMT;                                                        \
    __builtin_amdgcn_s_setprio(1);                                     \
    _Pragma("unroll")                                                  \
    for (int mm = 0; mm < 4; ++mm)                                     \
      _Pragma("unroll")                                                \
      for (int n = 0; n < 4; ++n)                                      \
        acc[(MH) * 4 + mm][n] = __builtin_amdgcn_mfma_f32_16x16x32_bf16( \
            AFC[mm], BFC[n], acc[(MH) * 4 + mm][n], 0, 0, 0);          \
    __builtin_amdgcn_s_setprio(0);                                     \
    VMSTMT;                                                            \
    BAR();                                                             \
  } while (0)

__global__ __launch_bounds__(512, 1) void gemm_fused_kernel(
    const u16* __restrict__ Ab, const u16* __restrict__ Bb,
    const float* __restrict__ bnon, float* __restrict__ out) {
  // 8 slots of 16 KB: [buf][mat A/B][k-half]. Slot = 256 rows x 32 bf16.
  // phys = pair*128B + ((((row&1)<<2)|chunk16) ^ (pair&7))*16B  (involution)
  __shared__ __attribute__((aligned(16))) u16 LDSu[65536];
  char* LDSc = (char*)LDSu;

  const int bid = blockIdx.x;
  const int swz = ((bid & 7) << 6) | (bid >> 3);   // 512 % 8 == 0: bijective XCD swizzle
  const int bm = swz >> 4, bn = swz & 15;
  const int rowBase = bm * 256, colBase = bn * 256;

  const int tid  = threadIdx.x;
  const int w    = tid >> 6, lane = tid & 63;
  const int wm = w >> 2, wn = w & 3;               // 2 x 4 wave grid
  const int wRow = wm * 128, wCol = wn * 64;       // per-wave 128x64 output
  const int l15 = lane & 15, g = lane >> 4;

  const int laneOff = ((l15 >> 1) << 7) +
                      (((((l15 & 1) << 2) | g) ^ ((l15 >> 1) & 7)) << 4);

  int rowS[2], colS[2];
#pragma unroll
  for (int is = 0; is < 2; ++is) {
    const int d = is * 8192 + tid * 16;
    const int b = d ^ ((d >> 3) & 0x70);
    rowS[is] = ((b >> 7) << 1) | ((b >> 6) & 1);
    colS[is] = (b >> 1) & 31;
  }
  const u16* pA0 = Ab + (size_t)(rowBase + rowS[0]) * K_TOT + colS[0];
  const u16* pA1 = Ab + (size_t)(rowBase + rowS[1]) * K_TOT + colS[1];
  const u16* pB0 = Bb + (size_t)(colBase + rowS[0]) * K_TOT + colS[0];
  const u16* pB1 = Bb + (size_t)(colBase + rowS[1]) * K_TOT + colS[1];

  // bias: load, keep alive, and fully retire so the vmcnt ledger stays clean
  float bn4[4];
#pragma unroll
  for (int n = 0; n < 4; ++n) bn4[n] = bnon[colBase + wCol + n * 16 + l15];
  asm volatile("" :: "v"(bn4[0]), "v"(bn4[1]), "v"(bn4[2]), "v"(bn4[3]));
  VM0();

  auto stageU = [&](int mat, int buf, int ks, int t64) {
    const u16* s0 = (mat ? pB0 : pA0) + t64 + ks * 32;
    const u16* s1 = (mat ? pB1 : pA1) + t64 + ks * 32;
    char* dst = LDSc + buf * 65536 + mat * 32768 + ks * 16384 + tid * 16;
    GLOAD16(s0, dst);
    GLOAD16(s1, dst + 8192);
  };

  f32x4 acc[8][4] = {};
  bf16x8 afA[4], afB[4], bfrA[4], bfrB[4];

  // prologue: tile0 full (buf0) + tile1 k0 (buf1) = 12 gloads
  stageU(0, 0, 0, 0); stageU(1, 0, 0, 0);
  stageU(0, 0, 1, 0); stageU(1, 0, 1, 0);
  stageU(0, 1, 0, 64); stageU(1, 1, 0, 64);
  asm volatile("s_waitcnt vmcnt(8)" ::: "memory"); // (0,*,k0) resident
  BAR();
  RD_BF(bfrA, 0, 0); RD_AF(afA, 0, 0, 0);          // p0 operands

  for (int T = 0; T < NT - 2; T += 2) {
    if (T == T_SPLIT) {
      // acc == x_nc @ W_non^T complete; in-place: sigmoid(acc+b) - 1
#pragma unroll
      for (int m = 0; m < 8; ++m)
#pragma unroll
        for (int n = 0; n < 4; ++n)
#pragma unroll
          for (int j = 0; j < 4; ++j) {
            const float t = acc[m][n][j] + bn4[n];
            acc[m][n][j] = 1.0f / (1.0f + __expf(-t)) - 1.0f;
          }
    }
    const int t1 = (T + 1) * 64, t2 = (T + 2) * 64, t3 = (T + 3) * 64;
    // p0..p3: buf0 (tile T); p4..p7: buf1 (tile T+1). Reads lead by 1 phase.
    PHASE(afA, bfrA, 0, RD_AF(afB, 0, 0, 1),                           stageU(0, 1, 1, t1), VM6());
    PHASE(afB, bfrA, 1, { RD_BF(bfrB, 0, 1); RD_AF(afA, 0, 1, 0); },   stageU(1, 1, 1, t1), VNONE);
    PHASE(afA, bfrB, 0, RD_AF(afB, 0, 1, 1),                           stageU(0, 0, 0, t2), VM6());
    PHASE(afB, bfrB, 1, { RD_BF(bfrA, 1, 0); RD_AF(afA, 1, 0, 0); },   stageU(1, 0, 0, t2), VNONE);
    PHASE(afA, bfrA, 0, RD_AF(afB, 1, 0, 1),                           stageU(0, 0, 1, t2), VM6());
    PHASE(afB, bfrA, 1, { RD_BF(bfrB, 1, 1); RD_AF(afA, 1, 1, 0); },   stageU(1, 0, 1, t2), VNONE);
    PHASE(afA, bfrB, 0, RD_AF(afB, 1, 1, 1),                           stageU(0, 1, 0, t3), VM6());
    PHASE(afB, bfrB, 1, { RD_BF(bfrA, 0, 0); RD_AF(afA, 0, 0, 0); },   stageU(1, 1, 0, t3), VNONE);
  }

  {   // tail body T = NT-2: no further buf0/next-buf1 staging; full drains
    const int t1 = (NT - 1) * 64;
    PHASE(afA, bfrA, 0, RD_AF(afB, 0, 0, 1),                           stageU(0, 1, 1, t1), VM0());
    PHASE(afB, bfrA, 1, { RD_BF(bfrB, 0, 1); RD_AF(afA, 0, 1, 0); },   stageU(1, 1, 1, t1), VNONE);
    PHASE(afA, bfrB, 0, RD_AF(afB, 0, 1, 1),                           VNONE,               VM0());
    PHASE(afB, bfrB, 1, { RD_BF(bfrA, 1, 0); RD_AF(afA, 1, 0, 0); },   VNONE,               VNONE);
    PHASE(afA, bfrA, 0, RD_AF(afB, 1, 0, 1),                           VNONE,               VM0());
    PHASE(afB, bfrA, 1, { RD_BF(bfrB, 1, 1); RD_AF(afA, 1, 1, 0); },   VNONE,               VNONE);
    PHASE(afA, bfrB, 0, RD_AF(afB, 1, 1, 1),                           VNONE,               VM0());
    PHASE(afB, bfrB, 1, VNONE,                                         VNONE,               VNONE);
  }

  // epilogue: Hill. C/D layout col=lane&15, row=(lane>>4)*4+j  [m89/m91]
#pragma unroll
  for (int m = 0; m < 8; ++m) {
#pragma unroll
    for (int n = 0; n < 4; ++n) {
#pragma unroll
      for (int j = 0; j < 4; ++j) {
        const int r = rowBase + wRow + m * 16 + g * 4 + j;
        const int c = colBase + wCol + n * 16 + l15;
        const float pre = acc[m][n][j];
        const float xn = pre * pre;
        out[(size_t)r * OUT_F + c] = xn / (0.25f + xn);
      }
    }
  }
}

// ---------------- fallback (workspace too small): naive fp32
__global__ void naive_fused_kernel(const float* __restrict__ x,
                                   const float* __restrict__ Wnmda,
                                   const float* __restrict__ Wnon,
                                   const float* __restrict__ bnon,
                                   float* __restrict__ out) {
  const long long total = (long long)BATCHN * OUT_F;
  for (long long idx = (long long)blockIdx.x * blockDim.x + threadIdx.x;
       idx < total; idx += (long long)gridDim.x * blockDim.x) {
    const int b = (int)(idx / OUT_F);
    const int o = (int)(idx % OUT_F);
    float s = bnon[o];
    for (int k = 0; k < K_NON; ++k)
      s += x[(size_t)b * IN_F + IC_N + k] * Wnon[(size_t)o * K_NON + k];
    const float state = 1.0f / (1.0f + __expf(-s)) - 1.0f;
    float ca = 0.0f;
    for (int j = 0; j < IC_N; ++j)
      ca += x[(size_t)b * IN_F + j] * coefj(j) * Wnmda[(size_t)o * IC_N + j];
    const float pre = ca + state;
    const float xn = pre * pre;
    out[idx] = xn / (0.25f + xn);
  }
}

extern "C" void kernel_launch(void* const* d_in, const int* in_sizes, int n_in,
                              void* d_out, int out_size, void* d_ws, size_t ws_size,
                              hipStream_t stream) {
  const float* x     = (const float*)d_in[0];
  const float* Wnmda = (const float*)d_in[1];
  const float* Wnon  = (const float*)d_in[2];
  const float* bnon  = (const float*)d_in[3];
  float* out = (float*)d_out;

  const size_t needA = (size_t)BATCHN * K_TOT * sizeof(u16);  // ~81.8 MB
  const size_t needB = (size_t)OUT_F * K_TOT * sizeof(u16);   // ~40.9 MB

  if (ws_size < needA + needB) {
    naive_fused_kernel<<<8192, 256, 0, stream>>>(x, Wnmda, Wnon, bnon, out);
    return;
  }

  u16* Ab = (u16*)d_ws;
  u16* Bb = Ab + (size_t)BATCHN * K_TOT;

  pack_a_kernel<<<BATCHN, 256, 0, stream>>>(x, Ab);
  pack_b_kernel<<<OUT_F, 256, 0, stream>>>(Wnon, Wnmda, Bb);
  gemm_fused_kernel<<<512, 512, 0, stream>>>(Ab, Bb, bnon, out);
}

// Round 11
// 353.487 us; speedup vs baseline: 17.4568x; 1.0196x over previous
//
#include <hip/hip_runtime.h>
#include <hip/hip_bf16.h>
#include <cstdint>
#include <cstddef>

typedef unsigned short u16;
typedef __bf16 bf16x8 __attribute__((ext_vector_type(8)));
typedef float f32x4 __attribute__((ext_vector_type(4)));
typedef float f32x4u __attribute__((ext_vector_type(4), aligned(4)));  // 4B-aligned vector load

#define IN_F   4096
#define OUT_F  4096
#define IC_N   409      // int(4096*0.1)
#define K_NON  3687     // 4096-409
#define K_HI0  3712     // 58*64: sigmoid boundary (BK-aligned)
#define K_LO0  4121
#define K_HI1  4530
#define K_END  4939
#define K_TOT  4992     // 78*64
#define BATCHN 8192
#define NT     78       // K-tiles of 64
#define T_SPLIT 58      // body index where state transform applies

__device__ __forceinline__ u16 f2bf(float f) {          // RNE fp32->bf16
  uint32_t u = __float_as_uint(f);
  uint32_t r = (u + 0x7FFFu + ((u >> 16) & 1u)) >> 16;
  return (u16)r;
}
__device__ __forceinline__ float bf2f(u16 h) {
  return __uint_as_float(((uint32_t)h) << 16);
}
__device__ __forceinline__ float coefj(int j) {
  return (j == 0 || j == IC_N - 1) ? 1.0f : 2.0f;
}

// ---------------- fused pack (r5-verified bodies, one dispatch):
// blocks [0, BATCHN)          -> pack A row b
// blocks [BATCHN, BATCHN+OUT_F) -> pack B row b-BATCHN
__global__ __launch_bounds__(256) void pack_ab_kernel(const float* __restrict__ x,
                                                      const float* __restrict__ Wnmda,
                                                      const float* __restrict__ Wnon,
                                                      u16* __restrict__ Ab,
                                                      u16* __restrict__ Bb) {
  __shared__ u16 hbuf[IC_N];
  __shared__ u16 lbuf[IC_N];
  const int blk = blockIdx.x;
  if (blk < BATCHN) {
    // ---- pack A: [bf16(x_nc) | 0 | hi(xc*c) | lo(xc*c) | hi(xc*c) | 0]
    const int row = blk;
    const float* xr = x + (size_t)row * IN_F;
    for (int j = threadIdx.x; j < IC_N; j += 256) {
      const float v = xr[j] * coefj(j);
      const u16 h = f2bf(v);
      hbuf[j] = h;
      lbuf[j] = f2bf(v - bf2f(h));
    }
    __syncthreads();
    u16* outr = Ab + (size_t)row * K_TOT;
    for (int c8 = threadIdx.x; c8 < K_TOT / 8; c8 += 256) {
      const int kb = c8 * 8;
      u16 tmp[8] __attribute__((aligned(16)));
      if (kb + 8 <= K_NON) {
        const float* s = xr + IC_N + kb;
        const f32x4u v0 = *(const f32x4u*)s;
        const f32x4u v1 = *(const f32x4u*)(s + 4);
#pragma unroll
        for (int e = 0; e < 4; ++e) { tmp[e] = f2bf(v0[e]); tmp[4 + e] = f2bf(v1[e]); }
      } else if (kb < K_HI0) {
#pragma unroll
        for (int e = 0; e < 8; ++e) {
          const int k = kb + e;
          tmp[e] = (k < K_NON) ? f2bf(xr[IC_N + k]) : (u16)0;
        }
      } else {
#pragma unroll
        for (int e = 0; e < 8; ++e) {
          const int k = kb + e;
          u16 o;
          if (k < K_LO0)      o = hbuf[k - K_HI0];
          else if (k < K_HI1) o = lbuf[k - K_LO0];
          else if (k < K_END) o = hbuf[k - K_HI1];
          else                o = 0;
          tmp[e] = o;
        }
      }
      *(int4*)(outr + kb) = *(const int4*)tmp;
    }
  } else {
    // ---- pack B: [bf16(W_non) | 0 | hi(W_nmda) | hi(W_nmda) | lo(W_nmda) | 0]
    const int row = blk - BATCHN;
    const float* wr = Wnon + (size_t)row * K_NON;
    const float* wc = Wnmda + (size_t)row * IC_N;
    for (int j = threadIdx.x; j < IC_N; j += 256) {
      const float v = wc[j];
      const u16 h = f2bf(v);
      hbuf[j] = h;
      lbuf[j] = f2bf(v - bf2f(h));
    }
    __syncthreads();
    u16* outr = Bb + (size_t)row * K_TOT;
    for (int c8 = threadIdx.x; c8 < K_TOT / 8; c8 += 256) {
      const int kb = c8 * 8;
      u16 tmp[8] __attribute__((aligned(16)));
      if (kb + 8 <= K_NON) {
        const float* s = wr + kb;
        const f32x4u v0 = *(const f32x4u*)s;
        const f32x4u v1 = *(const f32x4u*)(s + 4);
#pragma unroll
        for (int e = 0; e < 4; ++e) { tmp[e] = f2bf(v0[e]); tmp[4 + e] = f2bf(v1[e]); }
      } else if (kb < K_HI0) {
#pragma unroll
        for (int e = 0; e < 8; ++e) {
          const int k = kb + e;
          tmp[e] = (k < K_NON) ? f2bf(wr[k]) : (u16)0;
        }
      } else {
#pragma unroll
        for (int e = 0; e < 8; ++e) {
          const int k = kb + e;
          u16 o;
          if (k < K_LO0)      o = hbuf[k - K_HI0];
          else if (k < K_HI1) o = hbuf[k - K_LO0];
          else if (k < K_END) o = lbuf[k - K_HI1];
          else                o = 0;
          tmp[e] = o;
        }
      }
      *(int4*)(outr + kb) = *(const int4*)tmp;
    }
  }
}

// ---------------- fused GEMM: 256x256, BK=64, 8 waves, single-barrier read-ahead
// pipeline (r9-verified: 313 us, MfmaUtil ~52, conflicts 0)
#define GLOAD16(gp, lp)                                           \
  __builtin_amdgcn_global_load_lds(                               \
      (const __attribute__((address_space(1))) void*)(gp),        \
      (__attribute__((address_space(3))) void*)(lp), 16, 0, 0)

#define MEMFENCE() asm volatile("" ::: "memory")
#define BAR() do { MEMFENCE(); __builtin_amdgcn_s_barrier(); MEMFENCE(); } while (0)
#define VM6()   asm volatile("s_waitcnt vmcnt(6)" ::: "memory")
#define VM0()   asm volatile("s_waitcnt vmcnt(0)" ::: "memory")
#define VNONE   ((void)0)

#define RD_AF(SET, BW, KK, MH) do {                                    \
    _Pragma("unroll")                                                  \
    for (int mm = 0; mm < 4; ++mm)                                     \
      SET[mm] = *(const bf16x8*)(LDSc + (BW) * 65536 + (KK) * 16384 +  \
                 (wRow + (MH) * 64 + mm * 16) * 64 + laneOff);         \
  } while (0)
#define RD_BF(SET, BW, KK) do {                                        \
    _Pragma("unroll")                                                  \
    for (int n = 0; n < 4; ++n)                                        \
      SET[n] = *(const bf16x8*)(LDSc + (BW) * 65536 + 32768 +          \
                (KK) * 16384 + (wCol + n * 16) * 64 + laneOff);        \
  } while (0)

// Phase: issue next phase's operand reads + one slot refill; MFMA on current
// operands (compiler inserts fine-grained lgkmcnt for their deps); counted
// vmcnt; barrier. Hazard ledger identical to verified r4.
#define PHASE(AFC, BFC, MH, NEXT_READS, STAGE_STMT, VMSTMT) do {       \
    NEXT_READS;                                                        \
    STAGE_STMT;                                                        \
    __builtin_amdgcn_s_setprio(1);                                     \
    _Pragma("unroll")                                                  \
    for (int mm = 0; mm < 4; ++mm)                                     \
      _Pragma("unroll")                                                \
      for (int n = 0; n < 4; ++n)                                      \
        acc[(MH) * 4 + mm][n] = __builtin_amdgcn_mfma_f32_16x16x32_bf16( \
            AFC[mm], BFC[n], acc[(MH) * 4 + mm][n], 0, 0, 0);          \
    __builtin_amdgcn_s_setprio(0);                                     \
    VMSTMT;                                                            \
    BAR();                                                             \
  } while (0)

__global__ __launch_bounds__(512, 1) void gemm_fused_kernel(
    const u16* __restrict__ Ab, const u16* __restrict__ Bb,
    const float* __restrict__ bnon, float* __restrict__ out) {
  // 8 slots of 16 KB: [buf][mat A/B][k-half]. Slot = 256 rows x 32 bf16.
  // phys = pair*128B + ((((row&1)<<2)|chunk16) ^ (pair&7))*16B  (involution)
  __shared__ __attribute__((aligned(16))) u16 LDSu[65536];
  char* LDSc = (char*)LDSu;

  const int bid = blockIdx.x;
  const int swz = ((bid & 7) << 6) | (bid >> 3);   // 512 % 8 == 0: bijective XCD swizzle
  const int bm = swz >> 4, bn = swz & 15;
  const int rowBase = bm * 256, colBase = bn * 256;

  const int tid  = threadIdx.x;
  const int w    = tid >> 6, lane = tid & 63;
  const int wm = w >> 2, wn = w & 3;               // 2 x 4 wave grid
  const int wRow = wm * 128, wCol = wn * 64;       // per-wave 128x64 output
  const int l15 = lane & 15, g = lane >> 4;

  const int laneOff = ((l15 >> 1) << 7) +
                      (((((l15 & 1) << 2) | g) ^ ((l15 >> 1) & 7)) << 4);

  int rowS[2], colS[2];
#pragma unroll
  for (int is = 0; is < 2; ++is) {
    const int d = is * 8192 + tid * 16;
    const int b = d ^ ((d >> 3) & 0x70);
    rowS[is] = ((b >> 7) << 1) | ((b >> 6) & 1);
    colS[is] = (b >> 1) & 31;
  }
  const u16* pA0 = Ab + (size_t)(rowBase + rowS[0]) * K_TOT + colS[0];
  const u16* pA1 = Ab + (size_t)(rowBase + rowS[1]) * K_TOT + colS[1];
  const u16* pB0 = Bb + (size_t)(colBase + rowS[0]) * K_TOT + colS[0];
  const u16* pB1 = Bb + (size_t)(colBase + rowS[1]) * K_TOT + colS[1];

  // bias: load, keep alive, and fully retire so the vmcnt ledger stays clean
  float bn4[4];
#pragma unroll
  for (int n = 0; n < 4; ++n) bn4[n] = bnon[colBase + wCol + n * 16 + l15];
  asm volatile("" :: "v"(bn4[0]), "v"(bn4[1]), "v"(bn4[2]), "v"(bn4[3]));
  VM0();

  auto stageU = [&](int mat, int buf, int ks, int t64) {
    const u16* s0 = (mat ? pB0 : pA0) + t64 + ks * 32;
    const u16* s1 = (mat ? pB1 : pA1) + t64 + ks * 32;
    char* dst = LDSc + buf * 65536 + mat * 32768 + ks * 16384 + tid * 16;
    GLOAD16(s0, dst);
    GLOAD16(s1, dst + 8192);
  };

  f32x4 acc[8][4] = {};
  bf16x8 afA[4], afB[4], bfrA[4], bfrB[4];

  // prologue: tile0 full (buf0) + tile1 k0 (buf1) = 12 gloads
  stageU(0, 0, 0, 0); stageU(1, 0, 0, 0);
  stageU(0, 0, 1, 0); stageU(1, 0, 1, 0);
  stageU(0, 1, 0, 64); stageU(1, 1, 0, 64);
  asm volatile("s_waitcnt vmcnt(8)" ::: "memory"); // (0,*,k0) resident
  BAR();
  RD_BF(bfrA, 0, 0); RD_AF(afA, 0, 0, 0);          // p0 operands

  for (int T = 0; T < NT - 2; T += 2) {
    if (T == T_SPLIT) {
      // acc == x_nc @ W_non^T complete; in-place: sigmoid(acc+b) - 1
#pragma unroll
      for (int m = 0; m < 8; ++m)
#pragma unroll
        for (int n = 0; n < 4; ++n)
#pragma unroll
          for (int j = 0; j < 4; ++j) {
            const float t = acc[m][n][j] + bn4[n];
            acc[m][n][j] = 1.0f / (1.0f + __expf(-t)) - 1.0f;
          }
    }
    const int t1 = (T + 1) * 64, t2 = (T + 2) * 64, t3 = (T + 3) * 64;
    // p0..p3: buf0 (tile T); p4..p7: buf1 (tile T+1). Reads lead by 1 phase.
    PHASE(afA, bfrA, 0, RD_AF(afB, 0, 0, 1),                           stageU(0, 1, 1, t1), VM6());
    PHASE(afB, bfrA, 1, { RD_BF(bfrB, 0, 1); RD_AF(afA, 0, 1, 0); },   stageU(1, 1, 1, t1), VNONE);
    PHASE(afA, bfrB, 0, RD_AF(afB, 0, 1, 1),                           stageU(0, 0, 0, t2), VM6());
    PHASE(afB, bfrB, 1, { RD_BF(bfrA, 1, 0); RD_AF(afA, 1, 0, 0); },   stageU(1, 0, 0, t2), VNONE);
    PHASE(afA, bfrA, 0, RD_AF(afB, 1, 0, 1),                           stageU(0, 0, 1, t2), VM6());
    PHASE(afB, bfrA, 1, { RD_BF(bfrB, 1, 1); RD_AF(afA, 1, 1, 0); },   stageU(1, 0, 1, t2), VNONE);
    PHASE(afA, bfrB, 0, RD_AF(afB, 1, 1, 1),                           stageU(0, 1, 0, t3), VM6());
    PHASE(afB, bfrB, 1, { RD_BF(bfrA, 0, 0); RD_AF(afA, 0, 0, 0); },   stageU(1, 1, 0, t3), VNONE);
  }

  {   // tail body T = NT-2: no further buf0/next-buf1 staging; full drains
    const int t1 = (NT - 1) * 64;
    PHASE(afA, bfrA, 0, RD_AF(afB, 0, 0, 1),                           stageU(0, 1, 1, t1), VM0());
    PHASE(afB, bfrA, 1, { RD_BF(bfrB, 0, 1); RD_AF(afA, 0, 1, 0); },   stageU(1, 1, 1, t1), VNONE);
    PHASE(afA, bfrB, 0, RD_AF(afB, 0, 1, 1),                           VNONE,               VM0());
    PHASE(afB, bfrB, 1, { RD_BF(bfrA, 1, 0); RD_AF(afA, 1, 0, 0); },   VNONE,               VNONE);
    PHASE(afA, bfrA, 0, RD_AF(afB, 1, 0, 1),                           VNONE,               VM0());
    PHASE(afB, bfrA, 1, { RD_BF(bfrB, 1, 1); RD_AF(afA, 1, 1, 0); },   VNONE,               VNONE);
    PHASE(afA, bfrB, 0, RD_AF(afB, 1, 1, 1),                           VNONE,               VM0());
    PHASE(afB, bfrB, 1, VNONE,                                         VNONE,               VNONE);
  }

  // epilogue: Hill. C/D layout col=lane&15, row=(lane>>4)*4+j  [m89/m91]
#pragma unroll
  for (int m = 0; m < 8; ++m) {
#pragma unroll
    for (int n = 0; n < 4; ++n) {
#pragma unroll
      for (int j = 0; j < 4; ++j) {
        const int r = rowBase + wRow + m * 16 + g * 4 + j;
        const int c = colBase + wCol + n * 16 + l15;
        const float pre = acc[m][n][j];
        const float xn = pre * pre;
        out[(size_t)r * OUT_F + c] = xn / (0.25f + xn);
      }
    }
  }
}

// ---------------- fallback (workspace too small): naive fp32
__global__ void naive_fused_kernel(const float* __restrict__ x,
                                   const float* __restrict__ Wnmda,
                                   const float* __restrict__ Wnon,
                                   const float* __restrict__ bnon,
                                   float* __restrict__ out) {
  const long long total = (long long)BATCHN * OUT_F;
  for (long long idx = (long long)blockIdx.x * blockDim.x + threadIdx.x;
       idx < total; idx += (long long)gridDim.x * blockDim.x) {
    const int b = (int)(idx / OUT_F);
    const int o = (int)(idx % OUT_F);
    float s = bnon[o];
    for (int k = 0; k < K_NON; ++k)
      s += x[(size_t)b * IN_F + IC_N + k] * Wnon[(size_t)o * K_NON + k];
    const float state = 1.0f / (1.0f + __expf(-s)) - 1.0f;
    float ca = 0.0f;
    for (int j = 0; j < IC_N; ++j)
      ca += x[(size_t)b * IN_F + j] * coefj(j) * Wnmda[(size_t)o * IC_N + j];
    const float pre = ca + state;
    const float xn = pre * pre;
    out[idx] = xn / (0.25f + xn);
  }
}

extern "C" void kernel_launch(void* const* d_in, const int* in_sizes, int n_in,
                              void* d_out, int out_size, void* d_ws, size_t ws_size,
                              hipStream_t stream) {
  const float* x     = (const float*)d_in[0];
  const float* Wnmda = (const float*)d_in[1];
  const float* Wnon  = (const float*)d_in[2];
  const float* bnon  = (const float*)d_in[3];
  float* out = (float*)d_out;

  const size_t needA = (size_t)BATCHN * K_TOT * sizeof(u16);  // ~81.8 MB
  const size_t needB = (size_t)OUT_F * K_TOT * sizeof(u16);   // ~40.9 MB

  if (ws_size < needA + needB) {
    naive_fused_kernel<<<8192, 256, 0, stream>>>(x, Wnmda, Wnon, bnon, out);
    return;
  }

  u16* Ab = (u16*)d_ws;
  u16* Bb = Ab + (size_t)BATCHN * K_TOT;

  pack_ab_kernel<<<BATCHN + OUT_F, 256, 0, stream>>>(x, Wnmda, Wnon, Ab, Bb);
  gemm_fused_kernel<<<512, 512, 0, stream>>>(Ab, Bb, bnon, out);
}